// Round 16
// baseline (282.408 us; speedup 1.0000x reference)
//
#include <hip/hip_runtime.h>
#include <stdint.h>

#define L1C 256
#define L2C 320
#define BC  64
#define DC  1024

typedef __bf16 bf16_t;
typedef __bf16 bf16x8 __attribute__((ext_vector_type(8)));
typedef __bf16 bf16x4 __attribute__((ext_vector_type(4)));
typedef float  f32x4  __attribute__((ext_vector_type(4)));

__device__ __forceinline__ void gload16(const void* g, void* l) {
  __builtin_amdgcn_global_load_lds(
      (__attribute__((address_space(1))) void*)g,
      (__attribute__((address_space(3))) void*)l, 16, 0, 0);
}

// ---------------- fused prep: converts + W2T + w2b + zb-zero ----------------
__global__ __launch_bounds__(256)
void prep_kernel(const float* __restrict__ r1, const float* __restrict__ r2,
                 bf16_t* __restrict__ XB,
                 const float* __restrict__ W1, bf16_t* __restrict__ WB1,
                 const float* __restrict__ W2, bf16_t* __restrict__ WB2,
                 bf16_t* __restrict__ W2T,
                 const float* __restrict__ b2, float* __restrict__ w2b,
                 float* __restrict__ zb) {
  __shared__ float buf[32 * 33];
  const int b = (int)blockIdx.x;
  if (b < 9216) {
    const float* src;
    size_t soff;
    if (b < 4096) { src = r1; soff = (size_t)b * 1024; }
    else          { src = r2; soff = (size_t)(b - 4096) * 1024; }
    const size_t doff = (size_t)b * 1024;
#pragma unroll
    for (int k = 0; k < 4; ++k) {
      const int i = threadIdx.x + k * 256;
      float4 v = ((const float4*)src)[soff + i];
      bf16x4 o = { (__bf16)v.x, (__bf16)v.y, (__bf16)v.z, (__bf16)v.w };
      ((bf16x4*)XB)[doff + i] = o;
    }
  } else if (b < 9728) {
    const int bb = b - 9216;
    const float* src = (bb < 256) ? W1 : W2;
    bf16_t* dst = (bb < 256) ? WB1 : WB2;
    const size_t base = (size_t)(bb & 255) * 1024;
#pragma unroll
    for (int k = 0; k < 4; ++k) {
      const int i = threadIdx.x + k * 256;
      float4 v = ((const float4*)src)[base + i];
      bf16x4 o = { (__bf16)v.x, (__bf16)v.y, (__bf16)v.z, (__bf16)v.w };
      ((bf16x4*)dst)[base + i] = o;
    }
  } else if (b < 10752) {
    const int bb = b - 9728;
    float (*tile)[33] = (float(*)[33])buf;
    const int tx = threadIdx.x & 31, ty = threadIdx.x >> 5;
    const int x0 = (bb & 31) * 32, y0 = (bb >> 5) * 32;
#pragma unroll
    for (int k = 0; k < 32; k += 8)
      tile[ty + k][tx] = W2[(size_t)(y0 + ty + k) * 1024 + x0 + tx];
    __syncthreads();
#pragma unroll
    for (int k = 0; k < 32; k += 8)
      W2T[(size_t)(x0 + ty + k) * 1024 + y0 + tx] = (bf16_t)tile[tx][ty + k];
  } else if (b < 10816) {
    const int bb = b - 10752;
    float (*red)[17] = (float(*)[17])buf;
    const int dt = threadIdx.x & 15, kg = threadIdx.x >> 4;
    const int d = bb * 16 + dt;
    float s = 0.f;
    for (int k = kg * 64; k < kg * 64 + 64; ++k)
      s += W2[(size_t)k * 1024 + d] * b2[k];
    red[kg][dt] = s;
    __syncthreads();
    if (kg == 0) {
      float t = 0.f;
#pragma unroll
      for (int g = 0; g < 16; ++g) t += red[g][dt];
      w2b[d] = t;
    }
  } else {
#pragma unroll
    for (int k = 0; k < 4; ++k) zb[threadIdx.x + k * 256] = 0.f;
  }
}

// ---------------- fused GEMM1 + G ------------------------------------------
// blocks [0,64):   G = W2T . W2T^T (full K=1024), 128x128 tile -> bf16 GB
// blocks [64,2368): h = relu(A W1^T + b1), 128^2 ring-3 XOR-swizzled (proven)
__global__ __launch_bounds__(256, 3)
void g1g_kernel(const bf16_t* __restrict__ A, const bf16_t* __restrict__ W,
                const float* __restrict__ bias, bf16_t* __restrict__ C,
                const bf16_t* __restrict__ W2T, bf16_t* __restrict__ GB) {
  __shared__ __align__(16) char lds[49152];
  const int blk = (int)blockIdx.x;

  if (blk < 64) {
    // ---- G block: 2-barrier 128^2 full-K GEMM (proven gemmK structure) ----
    bf16_t* sA = (bf16_t*)lds;
    bf16_t* sB = (bf16_t*)(lds + 8192);
    const int f = threadIdx.x;
    const int lane = f & 63, w4 = f >> 6;
    const int sRowG = f >> 2, sCol8G = (f & 3) * 8;
    const bf16_t* Ab = W2T + (size_t)(blk >> 3) * 128 * 1024 + (size_t)sRowG * 1024 + sCol8G;
    const bf16_t* Bb = W2T + (size_t)(blk & 7) * 128 * 1024 + (size_t)sRowG * 1024 + sCol8G;
    bf16_t* sAp = sA + sRowG * 32 + sCol8G;
    bf16_t* sBp = sB + sRowG * 32 + sCol8G;
    const int wrG = (w4 >> 1) * 64, wcG = (w4 & 1) * 64;
    const int rselG = lane & 15, koff2 = (lane >> 4) * 8;
    const bf16_t* rA = sA + (wrG + rselG) * 32 + koff2;
    const bf16_t* rB = sB + (wcG + rselG) * 32 + koff2;
    f32x4 acc[4][4] = {};
    for (int kt = 0; kt < 1024; kt += 32) {
      __syncthreads();
      gload16(Ab + kt,             sAp);
      gload16(Ab + kt + 64 * 1024, sAp + 64 * 32);
      gload16(Bb + kt,             sBp);
      gload16(Bb + kt + 64 * 1024, sBp + 64 * 32);
      asm volatile("s_waitcnt vmcnt(0)" ::: "memory");
      __syncthreads();
      bf16x8 af[4], bfv[4];
#pragma unroll
      for (int m = 0; m < 4; ++m) af[m] = *(const bf16x8*)(rA + m * 16 * 32);
#pragma unroll
      for (int n = 0; n < 4; ++n) bfv[n] = *(const bf16x8*)(rB + n * 16 * 32);
#pragma unroll
      for (int m = 0; m < 4; ++m)
#pragma unroll
        for (int n = 0; n < 4; ++n)
          acc[m][n] = __builtin_amdgcn_mfma_f32_16x16x32_bf16(af[m], bfv[n], acc[m][n], 0, 0, 0);
    }
    const int row0 = (blk >> 3) * 128 + wrG + (lane >> 4) * 4;
    const int col0 = (blk & 7) * 128 + wcG + rselG;
#pragma unroll
    for (int n = 0; n < 4; ++n) {
      const int c = col0 + n * 16;
#pragma unroll
      for (int m = 0; m < 4; ++m) {
        const int r = row0 + m * 16;
#pragma unroll
        for (int q = 0; q < 4; ++q)
          GB[(size_t)(r + q) * 1024 + c] = (bf16_t)acc[m][n][q];
      }
    }
    return;
  }

  // ---- gemm1 block ----
  const int bid = blk - 64;
  const int wg = (bid & 7) * 288 + (bid >> 3);
  const int mt = wg >> 3, nt = wg & 7;

  const int t = threadIdx.x;
  const int lane = t & 63, w = t >> 6;
  const int sRow = t >> 2;
  const int sCol8 = (((t & 3) ^ ((t >> 3) & 3))) * 8;   // pre-swizzled source chunk
  const int t16 = t * 16;

  const bf16_t* A0 = A + (size_t)(mt * 128 + sRow) * 1024 + sCol8;
  const bf16_t* A1 = A0 + (size_t)64 * 1024;
  const bf16_t* B0 = W + (size_t)(nt * 128 + sRow) * 1024 + sCol8;
  const bf16_t* B1 = B0 + (size_t)64 * 1024;

  const int wr = (w >> 1) * 64, wc = (w & 1) * 64;
  const int rsel = lane & 15, hi = lane >> 4;
  const int kchunk = (hi ^ ((rsel >> 1) & 3)) << 4;
  const int offA = ((wr + rsel) << 6) + kchunk;
  const int offB = 8192 + ((wc + rsel) << 6) + kchunk;

  f32x4 acc[4][4] = {};

  // prologue: stage tiles 0,1
#pragma unroll
  for (int p = 0; p < 2; ++p) {
    char* db = lds + p * 16384;
    gload16(A0 + p * 32, db + t16);
    gload16(A1 + p * 32, db + 4096 + t16);
    gload16(B0 + p * 32, db + 8192 + t16);
    gload16(B1 + p * 32, db + 12288 + t16);
  }
  asm volatile("s_waitcnt vmcnt(4)" ::: "memory");   // tile 0 resident
  __builtin_amdgcn_s_barrier();
  __builtin_amdgcn_sched_barrier(0);

  int cur = 0;
#pragma unroll 1
  for (int tt = 0; tt < 32; ++tt) {
    const char* rb = lds + cur * 16384;
    int nx = cur + 2; if (nx >= 3) nx -= 3;
    char* sb = lds + nx * 16384;             // buffer of tile tt-1 (dead) -> tt+2
    const int ks = (tt + 2) * 32;
    bf16x8 af[4], bfv[4];
#pragma unroll
    for (int m = 0; m < 4; ++m) af[m] = *(const bf16x8*)(rb + offA + m * 1024);
#pragma unroll
    for (int n = 0; n < 4; ++n) bfv[n] = *(const bf16x8*)(rb + offB + n * 1024);
    if (tt < 30) {
      gload16(A0 + ks, sb + t16);
      gload16(A1 + ks, sb + 4096 + t16);
      gload16(B0 + ks, sb + 8192 + t16);
      gload16(B1 + ks, sb + 12288 + t16);
    }
    __builtin_amdgcn_s_setprio(1);
#pragma unroll
    for (int m = 0; m < 4; ++m)
#pragma unroll
      for (int n = 0; n < 4; ++n)
        acc[m][n] = __builtin_amdgcn_mfma_f32_16x16x32_bf16(af[m], bfv[n], acc[m][n], 0, 0, 0);
    __builtin_amdgcn_s_setprio(0);
    if (tt < 30)       asm volatile("s_waitcnt vmcnt(4)" ::: "memory");
    else if (tt == 30) asm volatile("s_waitcnt vmcnt(0)" ::: "memory");
    __builtin_amdgcn_s_barrier();
    __builtin_amdgcn_sched_barrier(0);
    cur = (cur + 1 == 3) ? 0 : cur + 1;
  }

  const int row0 = mt * 128 + wr + hi * 4;
  const int col0 = nt * 128 + wc + rsel;
  float bv[4];
#pragma unroll
  for (int n = 0; n < 4; ++n) bv[n] = bias[col0 + n * 16];
#pragma unroll
  for (int m = 0; m < 4; ++m) {
#pragma unroll
    for (int q = 0; q < 4; ++q) {
      const size_t rr = (size_t)(row0 + m * 16 + q) * 1024;
#pragma unroll
      for (int n = 0; n < 4; ++n) {
        float v = fmaxf(acc[m][n][q] + bv[n], 0.f);
        C[rr + col0 + n * 16] = (bf16_t)v;
      }
    }
  }
}

// ---------------- fused z1 GEMM + t GEMV ------------------------------------
// blocks [0,256):    z1 = h1 G  (256x256 8-wave proven mlp_gemm8 body)
// blocks [256,4864): t[r] = H[r,:].w2b, 8 waves x 1 row (proven t math)
__global__ __launch_bounds__(512, 2)
void z1t_kernel(const bf16_t* __restrict__ A, const bf16_t* __restrict__ W,
                const float* __restrict__ bias, bf16_t* __restrict__ C,
                const float* __restrict__ w2b,
                float* __restrict__ tT1, float* __restrict__ tT2) {
  __shared__ __align__(16) char lds[131072];
  const int blk = (int)blockIdx.x;

  if (blk >= 256) {
    // ---- t GEMV: wave wv handles row r ----
    const int wv = threadIdx.x >> 6, lane = threadIdx.x & 63;
    const int r = (blk - 256) * 8 + wv;
    const bf16_t* hrow = A + (size_t)r * 1024;   // A == H here
    float s = 0.f;
#pragma unroll
    for (int h = 0; h < 2; ++h) {
      bf16x8 v = *(const bf16x8*)(hrow + h * 512 + lane * 8);
#pragma unroll
      for (int e = 0; e < 8; ++e) s += (float)v[e] * w2b[h * 512 + lane * 8 + e];
    }
#pragma unroll
    for (int off = 32; off; off >>= 1) s += __shfl_xor(s, off);
    if (lane == 0) {
      const int b = r & 63;
      if (r < 16384) tT1[b * L1C + (r >> 6)] = s;
      else           tT2[b * L2C + ((r - 16384) >> 6)] = s;
    }
    return;
  }

  // ---- z1 GEMM block (Mtiles=64, nwg=256) ----
  const int wg  = (blk & 7) * 32 + (blk >> 3);
  const int mt = wg >> 2, nt = wg & 3;

  const int t    = threadIdx.x;
  const int lane = t & 63, wid = t >> 6;
  const int wm = wid >> 2, wn = wid & 3;
  const int rsel = lane & 15, hi = lane >> 4;
  const int t16 = t * 16;

  const int P0 = t16, P1 = 8192 + t16;
  const int Lg0 = P0 ^ ((P0 >> 3) & 0x30);
  const int Lg1 = P1 ^ ((P1 >> 3) & 0x30);
  const int rS0 = Lg0 >> 6, cS0 = (Lg0 & 63) >> 1;
  const int rS1 = Lg1 >> 6, cS1 = (Lg1 & 63) >> 1;
  const bf16_t* pA0 = A + (size_t)(mt * 256 + rS0) * 1024 + cS0;
  const bf16_t* pA1 = A + (size_t)(mt * 256 + rS1) * 1024 + cS1;
  const bf16_t* pB0 = W + (size_t)(nt * 256 + rS0) * 1024 + cS0;
  const bf16_t* pB1 = W + (size_t)(nt * 256 + rS1) * 1024 + cS1;

  const int kchunk = (hi ^ ((rsel >> 1) & 3)) << 4;
  const int offA = ((wm * 128 + rsel) << 6) + kchunk;
  const int offB = 16384 + ((wn * 64 + rsel) << 6) + kchunk;

  f32x4 acc[8][4] = {};
  bf16x8 bfr[4];

#pragma unroll
  for (int p = 0; p < 3; ++p) {
    char* db = lds + p * 32768;
    gload16(pA0 + p * 32, db + t16);
    gload16(pA1 + p * 32, db + 8192 + t16);
    gload16(pB0 + p * 32, db + 16384 + t16);
    gload16(pB1 + p * 32, db + 24576 + t16);
  }
  asm volatile("s_waitcnt vmcnt(8)" ::: "memory");
  __builtin_amdgcn_s_barrier();
  __builtin_amdgcn_sched_barrier(0);

#pragma unroll 1
  for (int tt = 0; tt < 32; ++tt) {
    const char* rb = lds + (tt & 3) * 32768;
    char* sb = lds + ((tt + 3) & 3) * 32768;
    const int ks = (tt + 3) * 32;
    bf16x8 af[4];
#pragma unroll
    for (int m = 0; m < 4; ++m) af[m] = *(const bf16x8*)(rb + offA + m * 1024);
#pragma unroll
    for (int n = 0; n < 4; ++n) bfr[n] = *(const bf16x8*)(rb + offB + n * 1024);
    if (tt < 29) {
      gload16(pA0 + ks, sb + t16);
      gload16(pA1 + ks, sb + 8192 + t16);
    }
    __builtin_amdgcn_s_setprio(1);
#pragma unroll
    for (int m = 0; m < 4; ++m)
#pragma unroll
      for (int n = 0; n < 4; ++n)
        acc[m][n] = __builtin_amdgcn_mfma_f32_16x16x32_bf16(af[m], bfr[n], acc[m][n], 0, 0, 0);
    __builtin_amdgcn_s_setprio(0);
    __builtin_amdgcn_s_barrier();
    __builtin_amdgcn_sched_barrier(0);
#pragma unroll
    for (int m = 0; m < 4; ++m) af[m] = *(const bf16x8*)(rb + offA + (m + 4) * 1024);
    if (tt < 29) {
      gload16(pB0 + ks, sb + 16384 + t16);
      gload16(pB1 + ks, sb + 24576 + t16);
    }
    __builtin_amdgcn_s_setprio(1);
#pragma unroll
    for (int m = 0; m < 4; ++m)
#pragma unroll
      for (int n = 0; n < 4; ++n)
        acc[m + 4][n] = __builtin_amdgcn_mfma_f32_16x16x32_bf16(af[m], bfr[n], acc[m + 4][n], 0, 0, 0);
    __builtin_amdgcn_s_setprio(0);
    if (tt < 29)       asm volatile("s_waitcnt vmcnt(8)" ::: "memory");
    else if (tt == 29) asm volatile("s_waitcnt vmcnt(4)" ::: "memory");
    else if (tt == 30) asm volatile("s_waitcnt vmcnt(0)" ::: "memory");
    __builtin_amdgcn_s_barrier();
    __builtin_amdgcn_sched_barrier(0);
  }

  const int row0 = mt * 256 + wm * 128 + hi * 4;
  const int col0 = nt * 256 + wn * 64 + rsel;
  float bv[4];
#pragma unroll
  for (int n = 0; n < 4; ++n) bv[n] = bias[col0 + n * 16];
#pragma unroll
  for (int m = 0; m < 8; ++m) {
#pragma unroll
    for (int q = 0; q < 4; ++q) {
      const size_t rr = (size_t)(row0 + m * 16 + q) * 1024;
#pragma unroll
      for (int n = 0; n < 4; ++n) {
        float v = acc[m][n][q] + bv[n];
        C[rr + col0 + n * 16] = (bf16_t)v;
      }
    }
  }
}

// ---------------- pool split-K GEMM: U(256x1024) * W2^T, 8 K-slices ----------
__global__ __launch_bounds__(256)
void pool_gemmK(const bf16_t* __restrict__ A, const bf16_t* __restrict__ W,
                float* __restrict__ P) {
  const int slice = (int)blockIdx.x >> 4;
  const int tl = (int)blockIdx.x & 15;
  const int mt = tl >> 3, nt = tl & 7;
  const int koff = slice * 128;

  const int f = threadIdx.x;
  const int lane = f & 63, w = f >> 6;
  const int sRow = f >> 2, sCol8 = (f & 3) * 8;

  const bf16_t* Ab = A + (size_t)mt * 128 * 1024 + (size_t)sRow * 1024 + sCol8;
  const bf16_t* Bb = W + (size_t)nt * 128 * 1024 + (size_t)sRow * 1024 + sCol8;

  __shared__ __align__(16) bf16_t sA[128 * 32];
  __shared__ __align__(16) bf16_t sB[128 * 32];
  bf16_t* sAp = sA + sRow * 32 + sCol8;
  bf16_t* sBp = sB + sRow * 32 + sCol8;

  const int wr = (w >> 1) * 64, wc = (w & 1) * 64;
  const int rsel = lane & 15, koff2 = (lane >> 4) * 8;
  const bf16_t* rA = sA + (wr + rsel) * 32 + koff2;
  const bf16_t* rB = sB + (wc + rsel) * 32 + koff2;

  f32x4 acc[4][4] = {};
  for (int kt = koff; kt < koff + 128; kt += 32) {
    __syncthreads();
    gload16(Ab + kt,             sAp);
    gload16(Ab + kt + 64 * 1024, sAp + 64 * 32);
    gload16(Bb + kt,             sBp);
    gload16(Bb + kt + 64 * 1024, sBp + 64 * 32);
    asm volatile("s_waitcnt vmcnt(0)" ::: "memory");
    __syncthreads();
    bf16x8 af[4], bfv[4];
#pragma unroll
    for (int m = 0; m < 4; ++m) af[m] = *(const bf16x8*)(rA + m * 16 * 32);
#pragma unroll
    for (int n = 0; n < 4; ++n) bfv[n] = *(const bf16x8*)(rB + n * 16 * 32);
#pragma unroll
    for (int m = 0; m < 4; ++m)
#pragma unroll
      for (int n = 0; n < 4; ++n)
        acc[m][n] = __builtin_amdgcn_mfma_f32_16x16x32_bf16(af[m], bfv[n], acc[m][n], 0, 0, 0);
  }

  float* Pb = P + (size_t)slice * 262144;
  const int row0 = mt * 128 + wr + (lane >> 4) * 4;
  const int col0 = nt * 128 + wc + rsel;
#pragma unroll
  for (int n = 0; n < 4; ++n) {
    const int c = col0 + n * 16;
#pragma unroll
    for (int m = 0; m < 4; ++m) {
      const int r = row0 + m * 16;
#pragma unroll
      for (int q = 0; q < 4; ++q)
        Pb[(size_t)(r + q) * 1024 + c] = acc[m][n][q];
    }
  }
}

// reduce 8 pool partials + bias, remap rows -> d_out
__global__ __launch_bounds__(256)
void pool_reduce(const float* __restrict__ Pp, const float* __restrict__ b2,
                 float* __restrict__ out) {
  const int idx = blockIdx.x * 256 + threadIdx.x;
  const int r = idx >> 10, c = idx & 1023;
  float s = b2[c];
#pragma unroll
  for (int sl = 0; sl < 8; ++sl) s += Pp[(size_t)sl * 262144 + idx];
  const int g = r >> 6, b = r & 63;
  out[(size_t)(g >> 1) * 131072 + (size_t)b * 2048 + (g & 1) * 1024 + c] = s;
}

// ---------------- logits: oz[b,i,j] = z1[b,i,:].h2[b,j,:] ----------------
__global__ __launch_bounds__(256)
void logits_gemm(const bf16_t* __restrict__ Y1, const bf16_t* __restrict__ Y2,
                 float* __restrict__ O) {
  const int wg = ((int)blockIdx.x & 7) * 48 + ((int)blockIdx.x >> 3);
  const int b = wg / 6, t6 = wg % 6;
  const int mt = t6 / 3, nt = t6 % 3;

  __shared__ __align__(16) char lds[65536];    // 4 bufs x (A 8KB + B 8KB)

  const int t = threadIdx.x;
  const int lane = t & 63, w = t >> 6;
  const int sRow = t >> 2;
  const int sCol8 = (((t & 3) ^ ((t >> 3) & 3))) * 8;   // pre-swizzled source chunk
  const int t16 = t * 16;

  const int i0 = mt * 128 + sRow;
  const int i1 = i0 + 64;
  int j0 = nt * 128 + sRow;      if (j0 > L2C - 1) j0 = L2C - 1;
  int j1 = nt * 128 + sRow + 64; if (j1 > L2C - 1) j1 = L2C - 1;
  const bf16_t* A0 = Y1 + ((size_t)i0 * BC + b) * DC + sCol8;
  const bf16_t* A1 = Y1 + ((size_t)i1 * BC + b) * DC + sCol8;
  const bf16_t* B0 = Y2 + ((size_t)j0 * BC + b) * DC + sCol8;
  const bf16_t* B1 = Y2 + ((size_t)j1 * BC + b) * DC + sCol8;

  const int wr = (w >> 1) * 64, wc = (w & 1) * 64;
  const int rsel = lane & 15, hi = lane >> 4;
  const int kchunk = (hi ^ ((rsel >> 1) & 3)) << 4;
  const int offA = ((wr + rsel) << 6) + kchunk;
  const int offB = 8192 + ((wc + rsel) << 6) + kchunk;

  f32x4 acc[4][4] = {};

  // prologue: stage tiles 0..2
#pragma unroll
  for (int p = 0; p < 3; ++p) {
    char* db = lds + p * 16384;
    gload16(A0 + p * 32, db + t16);
    gload16(A1 + p * 32, db + 4096 + t16);
    gload16(B0 + p * 32, db + 8192 + t16);
    gload16(B1 + p * 32, db + 12288 + t16);
  }
  asm volatile("s_waitcnt vmcnt(8)" ::: "memory");
  __builtin_amdgcn_s_barrier();
  __builtin_amdgcn_sched_barrier(0);

#pragma unroll 1
  for (int tt = 0; tt < 32; ++tt) {
    const char* rb = lds + (tt & 3) * 16384;
    char* sb = lds + ((tt + 3) & 3) * 16384;
    const int ks = (tt + 3) * 32;
    bf16x8 af[4], bfv[4];
#pragma unroll
    for (int m = 0; m < 4; ++m) af[m] = *(const bf16x8*)(rb + offA + m * 1024);
#pragma unroll
    for (int n = 0; n < 4; ++n) bfv[n] = *(const bf16x8*)(rb + offB + n * 1024);
    if (tt < 29) {
      gload16(A0 + ks, sb + t16);
      gload16(A1 + ks, sb + 4096 + t16);
      gload16(B0 + ks, sb + 8192 + t16);
      gload16(B1 + ks, sb + 12288 + t16);
    }
    __builtin_amdgcn_s_setprio(1);
#pragma unroll
    for (int m = 0; m < 4; ++m)
#pragma unroll
      for (int n = 0; n < 4; ++n)
        acc[m][n] = __builtin_amdgcn_mfma_f32_16x16x32_bf16(af[m], bfv[n], acc[m][n], 0, 0, 0);
    __builtin_amdgcn_s_setprio(0);
    if (tt < 29)       asm volatile("s_waitcnt vmcnt(8)" ::: "memory");
    else if (tt == 29) asm volatile("s_waitcnt vmcnt(4)" ::: "memory");
    else if (tt == 30) asm volatile("s_waitcnt vmcnt(0)" ::: "memory");
    __builtin_amdgcn_s_barrier();
    __builtin_amdgcn_sched_barrier(0);
  }

  float* Ob = O + (size_t)b * L1C * L2C;
  const int row0 = mt * 128 + wr + hi * 4;
  const int col0 = nt * 128 + wc + rsel;
#pragma unroll
  for (int n = 0; n < 4; ++n) {
    const int c = col0 + n * 16;
    if (c < L2C) {
#pragma unroll
      for (int m = 0; m < 4; ++m) {
        const int r = row0 + m * 16;
#pragma unroll
        for (int q = 0; q < 4; ++q)
          Ob[(size_t)(r + q) * L2C + c] = acc[m][n][q];
      }
    }
  }
}

// ---------------- softmax stats (with rank-1 terms t1,t2) ----------------
__global__ __launch_bounds__(256)
void row_stats(const float* __restrict__ O, const float* __restrict__ tT2,
               float* __restrict__ rowM, float* __restrict__ rowInv) {
  const int gw = blockIdx.x * 4 + (threadIdx.x >> 6);
  const int lane = threadIdx.x & 63;
  const int b = gw >> 8;
  const float* row = O + (size_t)gw * L2C;
  const float* t2 = tT2 + b * L2C;
  float v[5];
  float m = -1e30f;
#pragma unroll
  for (int t = 0; t < 5; ++t) { v[t] = row[t * 64 + lane] + t2[t * 64 + lane]; m = fmaxf(m, v[t]); }
#pragma unroll
  for (int off = 32; off; off >>= 1) m = fmaxf(m, __shfl_xor(m, off));
  float s = 0.f;
#pragma unroll
  for (int t = 0; t < 5; ++t) s += __expf(v[t] - m);
#pragma unroll
  for (int off = 32; off; off >>= 1) s += __shfl_xor(s, off);
  if (lane == 0) { rowM[gw] = m; rowInv[gw] = 1.f / s; }
}

__global__ __launch_bounds__(256)
void col_stats_c1(const float* __restrict__ O, const float* __restrict__ tT1,
                  const float* __restrict__ tT2,
                  const float* __restrict__ rowM, const float* __restrict__ rowInv,
                  float* __restrict__ colM, float* __restrict__ colInv,
                  float* __restrict__ c1) {
  const int b = blockIdx.x / 5, jb = blockIdx.x % 5;
  const int jl = threadIdx.x & 63, ig = threadIdx.x >> 6;
  const int j = jb * 64 + jl;
  const float* Ob = O + (size_t)b * L1C * L2C + j;
  const float* rM = rowM + b * L1C;
  const float* rI = rowInv + b * L1C;
  const float* t1 = tT1 + b * L1C;
  const float t2j = tT2[b * L2C + j];
  float m = -1e30f, s = 0.f, cp = 0.f;
  for (int i = ig; i < L1C; i += 4) {
    float ov = Ob[(size_t)i * L2C];
    float v = ov + t1[i];
    float mn = fmaxf(m, v);
    s = s * __expf(m - mn) + __expf(v - mn);
    m = mn;
    cp += __expf(ov + t2j - rM[i]) * rI[i];
  }
  __shared__ float sm[4][64], ss[4][64], sc[4][64];
  sm[ig][jl] = m; ss[ig][jl] = s; sc[ig][jl] = cp;
  __syncthreads();
  if (ig == 0) {
    for (int g = 1; g < 4; ++g) {
      float mg = sm[g][jl], sg = ss[g][jl];
      float mn = fmaxf(m, mg);
      s = s * __expf(m - mn) + sg * __expf(mg - mn);
      m = mn;
      cp += sc[g][jl];
    }
    colM[b * L2C + j] = m;
    colInv[b * L2C + j] = 1.f / s;
    c1[b * L2C + j] = cp;
  }
}

__global__ __launch_bounds__(256)
void c2_kernel(const float* __restrict__ O, const float* __restrict__ tT1,
               const float* __restrict__ colM, const float* __restrict__ colInv,
               float* __restrict__ c2) {
  const int gw = blockIdx.x * 4 + (threadIdx.x >> 6);
  const int lane = threadIdx.x & 63;
  const int b = gw >> 8;
  const float* row = O + (size_t)gw * L2C;
  const float* cM = colM + b * L2C;
  const float* cI = colInv + b * L2C;
  const float t1i = tT1[b * L1C + (gw & 255)];
  float s = 0.f;
#pragma unroll
  for (int t = 0; t < 5; ++t) {
    const int j = t * 64 + lane;
    s += __expf(row[j] + t1i - cM[j]) * cI[j];
  }
#pragma unroll
  for (int off = 32; off; off >>= 1) s += __shfl_xor(s, off);
  if (lane == 0) c2[gw] = s;
}

// ---------------- weighted h-sums -> U (256x1024 bf16) ----------------
__global__ __launch_bounds__(256)
void u_kernel(const bf16_t* __restrict__ H, const float* __restrict__ c1,
              const float* __restrict__ c2, bf16_t* __restrict__ Ub) {
  const int b = blockIdx.x >> 2;
  const int d = (blockIdx.x & 3) * 256 + threadIdx.x;
  const bf16_t* H2 = H + (size_t)L1C * BC * DC;
  float s1 = 0.f, s1c = 0.f, s2 = 0.f, s2c = 0.f;
  const float* c2b = c2 + b * L1C;
  for (int i = 0; i < L1C; ++i) {
    float v = (float)H[((size_t)i * BC + b) * DC + d];
    s1 += v; s1c += c2b[i] * v;
  }
  const float* c1b = c1 + b * L2C;
  for (int j = 0; j < L2C; ++j) {
    float v = (float)H2[((size_t)j * BC + b) * DC + d];
    s2 += v; s2c += c1b[j] * v;
  }
  Ub[(size_t)(0 * 64 + b) * 1024 + d] = (bf16_t)(s1  * (1.f / L1C));
  Ub[(size_t)(1 * 64 + b) * 1024 + d] = (bf16_t)(s2c * (1.f / L1C));
  Ub[(size_t)(2 * 64 + b) * 1024 + d] = (bf16_t)(s2  * (1.f / L2C));
  Ub[(size_t)(3 * 64 + b) * 1024 + d] = (bf16_t)(s1c * (1.f / L2C));
}

// ---------------- host ----------------
extern "C" void kernel_launch(void* const* d_in, const int* in_sizes, int n_in,
                              void* d_out, int out_size, void* d_ws, size_t ws_size,
                              hipStream_t stream) {
  const float* r1 = (const float*)d_in[0];
  const float* r2 = (const float*)d_in[1];
  const float* W1 = (const float*)d_in[2];
  const float* b1 = (const float*)d_in[3];
  const float* W2 = (const float*)d_in[4];
  const float* b2 = (const float*)d_in[5];
  float* out = (float*)d_out;
  char* ws = (char*)d_ws;

  const size_t M1 = (size_t)L1C * BC;   // 16384
  const size_t M2 = (size_t)L2C * BC;   // 20480
  const size_t Mt = M1 + M2;            // 36864

  size_t off = 0;
  bf16_t* XB  = (bf16_t*)(ws + off); off += Mt * DC * 2;        // 72MB: A-bf16, then Z + O
  bf16_t* HB  = (bf16_t*)(ws + off); off += Mt * DC * 2;        // 72MB, h; head reused as Ppart
  bf16_t* WB1 = (bf16_t*)(ws + off); off += (size_t)DC * DC * 2;
  bf16_t* WB2 = (bf16_t*)(ws + off); off += (size_t)DC * DC * 2;
  bf16_t* W2T = (bf16_t*)(ws + off); off += (size_t)DC * DC * 2;
  bf16_t* GB  = (bf16_t*)(ws + off); off += (size_t)DC * DC * 2;
  float* w2b   = (float*)(ws + off); off += 4096;
  float* zb    = (float*)(ws + off); off += 4096;
  float* tT1   = (float*)(ws + off); off += BC * L1C * 4;
  float* tT2   = (float*)(ws + off); off += BC * L2C * 4;
  float* rowM  = (float*)(ws + off); off += BC * L1C * 4;
  float* rowIv = (float*)(ws + off); off += BC * L1C * 4;
  float* colM  = (float*)(ws + off); off += BC * L2C * 4;
  float* colIv = (float*)(ws + off); off += BC * L2C * 4;
  float* c1v   = (float*)(ws + off); off += BC * L2C * 4;
  float* c2v   = (float*)(ws + off); off += BC * L1C * 4;
  bf16_t* Ub   = (bf16_t*)(ws + off); off += 256 * DC * 2;

  bf16_t* Z = XB;                                   // 16384x1024 bf16 (32MB)
  float*  O = (float*)((char*)XB + 35651584);       // 21MB logits
  float*  Ppart = (float*)HB;                       // 8MB (8 slices), HB dead then
  bf16_t* H2 = HB + M1 * DC;

  // 1. fused prep (converts + W2T + w2b + zb)
  prep_kernel<<<10817, 256, 0, stream>>>(r1, r2, XB, W1, WB1, W2, WB2, W2T,
                                         b2, w2b, zb);

  // 2. fused: G = W2T.W2T^T (blocks 0..63) + h = relu(x W1^T + b1) (rest)
  g1g_kernel<<<2368, 256, 0, stream>>>(XB, WB1, b1, HB, W2T, GB);

  // 3. fused: z1 = h1 G (blocks 0..255) + t = h.(W2^T b2) (blocks 256..4863)
  z1t_kernel<<<4864, 512, 0, stream>>>(HB, GB, zb, Z, w2b, tT1, tT2);

  // 4. oz[b,i,j] = z1 . h2
  logits_gemm<<<384, 256, 0, stream>>>(Z, H2, O);

  // 5. softmax stats with rank-1 corrections
  row_stats<<<4096, 256, 0, stream>>>(O, tT2, rowM, rowIv);
  col_stats_c1<<<320, 256, 0, stream>>>(O, tT1, tT2, rowM, rowIv, colM, colIv, c1v);
  c2_kernel<<<4096, 256, 0, stream>>>(O, tT1, colM, colIv, c2v);

  // 6. weighted h pools -> U;  out = U W2^T + b2, split-K + reduce
  u_kernel<<<256, 256, 0, stream>>>(HB, c1v, c2v, Ub);
  pool_gemmK<<<128, 256, 0, stream>>>(Ub, WB2, Ppart);
  pool_reduce<<<1024, 256, 0, stream>>>(Ppart, b2, out);
}

// Round 17
// 276.699 us; speedup vs baseline: 1.0206x; 1.0206x over previous
//
#include <hip/hip_runtime.h>
#include <stdint.h>

#define L1C 256
#define L2C 320
#define BC  64
#define DC  1024

typedef __bf16 bf16_t;
typedef __bf16 bf16x8 __attribute__((ext_vector_type(8)));
typedef __bf16 bf16x4 __attribute__((ext_vector_type(4)));
typedef float  f32x4  __attribute__((ext_vector_type(4)));

__device__ __forceinline__ void gload16(const void* g, void* l) {
  __builtin_amdgcn_global_load_lds(
      (__attribute__((address_space(1))) void*)g,
      (__attribute__((address_space(3))) void*)l, 16, 0, 0);
}

// ---------------- fused prep: converts + W2T + w2b + zb-zero ----------------
__global__ __launch_bounds__(256)
void prep_kernel(const float* __restrict__ r1, const float* __restrict__ r2,
                 bf16_t* __restrict__ XB,
                 const float* __restrict__ W1, bf16_t* __restrict__ WB1,
                 const float* __restrict__ W2, bf16_t* __restrict__ WB2,
                 bf16_t* __restrict__ W2T,
                 const float* __restrict__ b2, float* __restrict__ w2b,
                 float* __restrict__ zb) {
  __shared__ float buf[32 * 33];
  const int b = (int)blockIdx.x;
  if (b < 9216) {
    const float* src;
    size_t soff;
    if (b < 4096) { src = r1; soff = (size_t)b * 1024; }
    else          { src = r2; soff = (size_t)(b - 4096) * 1024; }
    const size_t doff = (size_t)b * 1024;
#pragma unroll
    for (int k = 0; k < 4; ++k) {
      const int i = threadIdx.x + k * 256;
      float4 v = ((const float4*)src)[soff + i];
      bf16x4 o = { (__bf16)v.x, (__bf16)v.y, (__bf16)v.z, (__bf16)v.w };
      ((bf16x4*)XB)[doff + i] = o;
    }
  } else if (b < 9728) {
    const int bb = b - 9216;
    const float* src = (bb < 256) ? W1 : W2;
    bf16_t* dst = (bb < 256) ? WB1 : WB2;
    const size_t base = (size_t)(bb & 255) * 1024;
#pragma unroll
    for (int k = 0; k < 4; ++k) {
      const int i = threadIdx.x + k * 256;
      float4 v = ((const float4*)src)[base + i];
      bf16x4 o = { (__bf16)v.x, (__bf16)v.y, (__bf16)v.z, (__bf16)v.w };
      ((bf16x4*)dst)[base + i] = o;
    }
  } else if (b < 10752) {
    const int bb = b - 9728;
    float (*tile)[33] = (float(*)[33])buf;
    const int tx = threadIdx.x & 31, ty = threadIdx.x >> 5;
    const int x0 = (bb & 31) * 32, y0 = (bb >> 5) * 32;
#pragma unroll
    for (int k = 0; k < 32; k += 8)
      tile[ty + k][tx] = W2[(size_t)(y0 + ty + k) * 1024 + x0 + tx];
    __syncthreads();
#pragma unroll
    for (int k = 0; k < 32; k += 8)
      W2T[(size_t)(x0 + ty + k) * 1024 + y0 + tx] = (bf16_t)tile[tx][ty + k];
  } else if (b < 10816) {
    const int bb = b - 10752;
    float (*red)[17] = (float(*)[17])buf;
    const int dt = threadIdx.x & 15, kg = threadIdx.x >> 4;
    const int d = bb * 16 + dt;
    float s = 0.f;
    for (int k = kg * 64; k < kg * 64 + 64; ++k)
      s += W2[(size_t)k * 1024 + d] * b2[k];
    red[kg][dt] = s;
    __syncthreads();
    if (kg == 0) {
      float t = 0.f;
#pragma unroll
      for (int g = 0; g < 16; ++g) t += red[g][dt];
      w2b[d] = t;
    }
  } else {
#pragma unroll
    for (int k = 0; k < 4; ++k) zb[threadIdx.x + k * 256] = 0.f;
  }
}

// ---------------- fused GEMM1 + G ------------------------------------------
// blocks [0,64):   G = W2T . W2T^T (full K=1024), 128x128 tile -> bf16 GB
// blocks [64,2368): h = relu(A W1^T + b1), 128^2 ring-3 XOR-swizzled (proven)
__global__ __launch_bounds__(256, 3)
void g1g_kernel(const bf16_t* __restrict__ A, const bf16_t* __restrict__ W,
                const float* __restrict__ bias, bf16_t* __restrict__ C,
                const bf16_t* __restrict__ W2T, bf16_t* __restrict__ GB) {
  __shared__ __align__(16) char lds[49152];
  const int blk = (int)blockIdx.x;

  if (blk < 64) {
    // ---- G block: 2-barrier 128^2 full-K GEMM (proven gemmK structure) ----
    bf16_t* sA = (bf16_t*)lds;
    bf16_t* sB = (bf16_t*)(lds + 8192);
    const int f = threadIdx.x;
    const int lane = f & 63, w4 = f >> 6;
    const int sRowG = f >> 2, sCol8G = (f & 3) * 8;
    const bf16_t* Ab = W2T + (size_t)(blk >> 3) * 128 * 1024 + (size_t)sRowG * 1024 + sCol8G;
    const bf16_t* Bb = W2T + (size_t)(blk & 7) * 128 * 1024 + (size_t)sRowG * 1024 + sCol8G;
    bf16_t* sAp = sA + sRowG * 32 + sCol8G;
    bf16_t* sBp = sB + sRowG * 32 + sCol8G;
    const int wrG = (w4 >> 1) * 64, wcG = (w4 & 1) * 64;
    const int rselG = lane & 15, koff2 = (lane >> 4) * 8;
    const bf16_t* rA = sA + (wrG + rselG) * 32 + koff2;
    const bf16_t* rB = sB + (wcG + rselG) * 32 + koff2;
    f32x4 acc[4][4] = {};
    for (int kt = 0; kt < 1024; kt += 32) {
      __syncthreads();
      gload16(Ab + kt,             sAp);
      gload16(Ab + kt + 64 * 1024, sAp + 64 * 32);
      gload16(Bb + kt,             sBp);
      gload16(Bb + kt + 64 * 1024, sBp + 64 * 32);
      asm volatile("s_waitcnt vmcnt(0)" ::: "memory");
      __syncthreads();
      bf16x8 af[4], bfv[4];
#pragma unroll
      for (int m = 0; m < 4; ++m) af[m] = *(const bf16x8*)(rA + m * 16 * 32);
#pragma unroll
      for (int n = 0; n < 4; ++n) bfv[n] = *(const bf16x8*)(rB + n * 16 * 32);
#pragma unroll
      for (int m = 0; m < 4; ++m)
#pragma unroll
        for (int n = 0; n < 4; ++n)
          acc[m][n] = __builtin_amdgcn_mfma_f32_16x16x32_bf16(af[m], bfv[n], acc[m][n], 0, 0, 0);
    }
    const int row0 = (blk >> 3) * 128 + wrG + (lane >> 4) * 4;
    const int col0 = (blk & 7) * 128 + wcG + rselG;
#pragma unroll
    for (int n = 0; n < 4; ++n) {
      const int c = col0 + n * 16;
#pragma unroll
      for (int m = 0; m < 4; ++m) {
        const int r = row0 + m * 16;
#pragma unroll
        for (int q = 0; q < 4; ++q)
          GB[(size_t)(r + q) * 1024 + c] = (bf16_t)acc[m][n][q];
      }
    }
    return;
  }

  // ---- gemm1 block ----
  const int bid = blk - 64;
  const int wg = (bid & 7) * 288 + (bid >> 3);
  const int mt = wg >> 3, nt = wg & 7;

  const int t = threadIdx.x;
  const int lane = t & 63, w = t >> 6;
  const int sRow = t >> 2;
  const int sCol8 = (((t & 3) ^ ((t >> 3) & 3))) * 8;   // pre-swizzled source chunk
  const int t16 = t * 16;

  const bf16_t* A0 = A + (size_t)(mt * 128 + sRow) * 1024 + sCol8;
  const bf16_t* A1 = A0 + (size_t)64 * 1024;
  const bf16_t* B0 = W + (size_t)(nt * 128 + sRow) * 1024 + sCol8;
  const bf16_t* B1 = B0 + (size_t)64 * 1024;

  const int wr = (w >> 1) * 64, wc = (w & 1) * 64;
  const int rsel = lane & 15, hi = lane >> 4;
  const int kchunk = (hi ^ ((rsel >> 1) & 3)) << 4;
  const int offA = ((wr + rsel) << 6) + kchunk;
  const int offB = 8192 + ((wc + rsel) << 6) + kchunk;

  f32x4 acc[4][4] = {};

  // prologue: stage tiles 0,1
#pragma unroll
  for (int p = 0; p < 2; ++p) {
    char* db = lds + p * 16384;
    gload16(A0 + p * 32, db + t16);
    gload16(A1 + p * 32, db + 4096 + t16);
    gload16(B0 + p * 32, db + 8192 + t16);
    gload16(B1 + p * 32, db + 12288 + t16);
  }
  asm volatile("s_waitcnt vmcnt(4)" ::: "memory");   // tile 0 resident
  __builtin_amdgcn_s_barrier();
  __builtin_amdgcn_sched_barrier(0);

  int cur = 0;
#pragma unroll 1
  for (int tt = 0; tt < 32; ++tt) {
    const char* rb = lds + cur * 16384;
    int nx = cur + 2; if (nx >= 3) nx -= 3;
    char* sb = lds + nx * 16384;             // buffer of tile tt-1 (dead) -> tt+2
    const int ks = (tt + 2) * 32;
    bf16x8 af[4], bfv[4];
#pragma unroll
    for (int m = 0; m < 4; ++m) af[m] = *(const bf16x8*)(rb + offA + m * 1024);
#pragma unroll
    for (int n = 0; n < 4; ++n) bfv[n] = *(const bf16x8*)(rb + offB + n * 1024);
    if (tt < 30) {
      gload16(A0 + ks, sb + t16);
      gload16(A1 + ks, sb + 4096 + t16);
      gload16(B0 + ks, sb + 8192 + t16);
      gload16(B1 + ks, sb + 12288 + t16);
    }
    __builtin_amdgcn_s_setprio(1);
#pragma unroll
    for (int m = 0; m < 4; ++m)
#pragma unroll
      for (int n = 0; n < 4; ++n)
        acc[m][n] = __builtin_amdgcn_mfma_f32_16x16x32_bf16(af[m], bfv[n], acc[m][n], 0, 0, 0);
    __builtin_amdgcn_s_setprio(0);
    if (tt < 30)       asm volatile("s_waitcnt vmcnt(4)" ::: "memory");
    else if (tt == 30) asm volatile("s_waitcnt vmcnt(0)" ::: "memory");
    __builtin_amdgcn_s_barrier();
    __builtin_amdgcn_sched_barrier(0);
    cur = (cur + 1 == 3) ? 0 : cur + 1;
  }

  const int row0 = mt * 128 + wr + hi * 4;
  const int col0 = nt * 128 + wc + rsel;
  float bv[4];
#pragma unroll
  for (int n = 0; n < 4; ++n) bv[n] = bias[col0 + n * 16];
#pragma unroll
  for (int m = 0; m < 4; ++m) {
#pragma unroll
    for (int q = 0; q < 4; ++q) {
      const size_t rr = (size_t)(row0 + m * 16 + q) * 1024;
#pragma unroll
      for (int n = 0; n < 4; ++n) {
        float v = fmaxf(acc[m][n][q] + bv[n], 0.f);
        C[rr + col0 + n * 16] = (bf16_t)v;
      }
    }
  }
}

// ---------------- t[r] = h[r,:] . w2b ----------------
__global__ __launch_bounds__(256)
void t_kernel(const bf16_t* __restrict__ H, const float* __restrict__ w2b,
              float* __restrict__ tT1, float* __restrict__ tT2) {
  const int wv = threadIdx.x >> 6, lane = threadIdx.x & 63;
  const int r = blockIdx.x * 4 + wv;
  const bf16_t* hrow = H + (size_t)r * 1024;
  float s = 0.f;
#pragma unroll
  for (int h = 0; h < 2; ++h) {
    bf16x8 v = *(const bf16x8*)(hrow + h * 512 + lane * 8);
#pragma unroll
    for (int e = 0; e < 8; ++e) s += (float)v[e] * w2b[h * 512 + lane * 8 + e];
  }
#pragma unroll
  for (int off = 32; off; off >>= 1) s += __shfl_xor(s, off);
  if (lane == 0) {
    const int b = r & 63;
    if (r < 16384) tT1[b * L1C + (r >> 6)] = s;
    else           tT2[b * L2C + ((r - 16384) >> 6)] = s;
  }
}

// ---------------- bf16 MLP GEMM, 256x256 tile, 8-wave (r2/r3 proven) ----------
__global__ __launch_bounds__(512, 2)
void mlp_gemm8(const bf16_t* __restrict__ A, const bf16_t* __restrict__ W,
               const float* __restrict__ bias, bf16_t* __restrict__ C,
               int Mtiles, int relu) {
  const int nwg = Mtiles * 4;
  const int cpx = nwg >> 3;
  const int wg  = ((int)blockIdx.x & 7) * cpx + ((int)blockIdx.x >> 3);
  const int mt = wg >> 2, nt = wg & 3;

  __shared__ __align__(16) char lds[131072];

  const int t    = threadIdx.x;
  const int lane = t & 63, wid = t >> 6;
  const int wm = wid >> 2, wn = wid & 3;
  const int rsel = lane & 15, hi = lane >> 4;
  const int t16 = t * 16;

  const int P0 = t16, P1 = 8192 + t16;
  const int Lg0 = P0 ^ ((P0 >> 3) & 0x30);
  const int Lg1 = P1 ^ ((P1 >> 3) & 0x30);
  const int rS0 = Lg0 >> 6, cS0 = (Lg0 & 63) >> 1;
  const int rS1 = Lg1 >> 6, cS1 = (Lg1 & 63) >> 1;
  const bf16_t* pA0 = A + (size_t)(mt * 256 + rS0) * 1024 + cS0;
  const bf16_t* pA1 = A + (size_t)(mt * 256 + rS1) * 1024 + cS1;
  const bf16_t* pB0 = W + (size_t)(nt * 256 + rS0) * 1024 + cS0;
  const bf16_t* pB1 = W + (size_t)(nt * 256 + rS1) * 1024 + cS1;

  const int kchunk = (hi ^ ((rsel >> 1) & 3)) << 4;
  const int offA = ((wm * 128 + rsel) << 6) + kchunk;
  const int offB = 16384 + ((wn * 64 + rsel) << 6) + kchunk;

  f32x4 acc[8][4] = {};
  bf16x8 bfr[4];

#pragma unroll
  for (int p = 0; p < 3; ++p) {
    char* db = lds + p * 32768;
    gload16(pA0 + p * 32, db + t16);
    gload16(pA1 + p * 32, db + 8192 + t16);
    gload16(pB0 + p * 32, db + 16384 + t16);
    gload16(pB1 + p * 32, db + 24576 + t16);
  }
  asm volatile("s_waitcnt vmcnt(8)" ::: "memory");
  __builtin_amdgcn_s_barrier();
  __builtin_amdgcn_sched_barrier(0);

#pragma unroll 1
  for (int tt = 0; tt < 32; ++tt) {
    const char* rb = lds + (tt & 3) * 32768;
    char* sb = lds + ((tt + 3) & 3) * 32768;
    const int ks = (tt + 3) * 32;
    bf16x8 af[4];
#pragma unroll
    for (int m = 0; m < 4; ++m) af[m] = *(const bf16x8*)(rb + offA + m * 1024);
#pragma unroll
    for (int n = 0; n < 4; ++n) bfr[n] = *(const bf16x8*)(rb + offB + n * 1024);
    if (tt < 29) {
      gload16(pA0 + ks, sb + t16);
      gload16(pA1 + ks, sb + 8192 + t16);
    }
    __builtin_amdgcn_s_setprio(1);
#pragma unroll
    for (int m = 0; m < 4; ++m)
#pragma unroll
      for (int n = 0; n < 4; ++n)
        acc[m][n] = __builtin_amdgcn_mfma_f32_16x16x32_bf16(af[m], bfr[n], acc[m][n], 0, 0, 0);
    __builtin_amdgcn_s_setprio(0);
    __builtin_amdgcn_s_barrier();
    __builtin_amdgcn_sched_barrier(0);
#pragma unroll
    for (int m = 0; m < 4; ++m) af[m] = *(const bf16x8*)(rb + offA + (m + 4) * 1024);
    if (tt < 29) {
      gload16(pB0 + ks, sb + 16384 + t16);
      gload16(pB1 + ks, sb + 24576 + t16);
    }
    __builtin_amdgcn_s_setprio(1);
#pragma unroll
    for (int m = 0; m < 4; ++m)
#pragma unroll
      for (int n = 0; n < 4; ++n)
        acc[m + 4][n] = __builtin_amdgcn_mfma_f32_16x16x32_bf16(af[m], bfr[n], acc[m + 4][n], 0, 0, 0);
    __builtin_amdgcn_s_setprio(0);
    if (tt < 29)       asm volatile("s_waitcnt vmcnt(8)" ::: "memory");
    else if (tt == 29) asm volatile("s_waitcnt vmcnt(4)" ::: "memory");
    else if (tt == 30) asm volatile("s_waitcnt vmcnt(0)" ::: "memory");
    __builtin_amdgcn_s_barrier();
    __builtin_amdgcn_sched_barrier(0);
  }

  const int row0 = mt * 256 + wm * 128 + hi * 4;
  const int col0 = nt * 256 + wn * 64 + rsel;
  float bv[4];
#pragma unroll
  for (int n = 0; n < 4; ++n) bv[n] = bias[col0 + n * 16];
#pragma unroll
  for (int m = 0; m < 8; ++m) {
#pragma unroll
    for (int q = 0; q < 4; ++q) {
      const size_t rr = (size_t)(row0 + m * 16 + q) * 1024;
#pragma unroll
      for (int n = 0; n < 4; ++n) {
        float v = acc[m][n][q] + bv[n];
        if (relu) v = fmaxf(v, 0.f);
        C[rr + col0 + n * 16] = (bf16_t)v;
      }
    }
  }
}

// ---------------- pool split-K GEMM: U(256x1024) * W2^T, 8 K-slices ----------
__global__ __launch_bounds__(256)
void pool_gemmK(const bf16_t* __restrict__ A, const bf16_t* __restrict__ W,
                float* __restrict__ P) {
  const int slice = (int)blockIdx.x >> 4;
  const int tl = (int)blockIdx.x & 15;
  const int mt = tl >> 3, nt = tl & 7;
  const int koff = slice * 128;

  const int f = threadIdx.x;
  const int lane = f & 63, w = f >> 6;
  const int sRow = f >> 2, sCol8 = (f & 3) * 8;

  const bf16_t* Ab = A + (size_t)mt * 128 * 1024 + (size_t)sRow * 1024 + sCol8;
  const bf16_t* Bb = W + (size_t)nt * 128 * 1024 + (size_t)sRow * 1024 + sCol8;

  __shared__ __align__(16) bf16_t sA[128 * 32];
  __shared__ __align__(16) bf16_t sB[128 * 32];
  bf16_t* sAp = sA + sRow * 32 + sCol8;
  bf16_t* sBp = sB + sRow * 32 + sCol8;

  const int wr = (w >> 1) * 64, wc = (w & 1) * 64;
  const int rsel = lane & 15, koff2 = (lane >> 4) * 8;
  const bf16_t* rA = sA + (wr + rsel) * 32 + koff2;
  const bf16_t* rB = sB + (wc + rsel) * 32 + koff2;

  f32x4 acc[4][4] = {};
  for (int kt = koff; kt < koff + 128; kt += 32) {
    __syncthreads();
    gload16(Ab + kt,             sAp);
    gload16(Ab + kt + 64 * 1024, sAp + 64 * 32);
    gload16(Bb + kt,             sBp);
    gload16(Bb + kt + 64 * 1024, sBp + 64 * 32);
    asm volatile("s_waitcnt vmcnt(0)" ::: "memory");
    __syncthreads();
    bf16x8 af[4], bfv[4];
#pragma unroll
    for (int m = 0; m < 4; ++m) af[m] = *(const bf16x8*)(rA + m * 16 * 32);
#pragma unroll
    for (int n = 0; n < 4; ++n) bfv[n] = *(const bf16x8*)(rB + n * 16 * 32);
#pragma unroll
    for (int m = 0; m < 4; ++m)
#pragma unroll
      for (int n = 0; n < 4; ++n)
        acc[m][n] = __builtin_amdgcn_mfma_f32_16x16x32_bf16(af[m], bfv[n], acc[m][n], 0, 0, 0);
  }

  float* Pb = P + (size_t)slice * 262144;
  const int row0 = mt * 128 + wr + (lane >> 4) * 4;
  const int col0 = nt * 128 + wc + rsel;
#pragma unroll
  for (int n = 0; n < 4; ++n) {
    const int c = col0 + n * 16;
#pragma unroll
    for (int m = 0; m < 4; ++m) {
      const int r = row0 + m * 16;
#pragma unroll
      for (int q = 0; q < 4; ++q)
        Pb[(size_t)(r + q) * 1024 + c] = acc[m][n][q];
    }
  }
}

// reduce 8 pool partials + bias, remap rows -> d_out
__global__ __launch_bounds__(256)
void pool_reduce(const float* __restrict__ Pp, const float* __restrict__ b2,
                 float* __restrict__ out) {
  const int idx = blockIdx.x * 256 + threadIdx.x;
  const int r = idx >> 10, c = idx & 1023;
  float s = b2[c];
#pragma unroll
  for (int sl = 0; sl < 8; ++sl) s += Pp[(size_t)sl * 262144 + idx];
  const int g = r >> 6, b = r & 63;
  out[(size_t)(g >> 1) * 131072 + (size_t)b * 2048 + (g & 1) * 1024 + c] = s;
}

// ---------------- logits: oz[b,i,j] = z1[b,i,:].h2[b,j,:] ----------------
__global__ __launch_bounds__(256)
void logits_gemm(const bf16_t* __restrict__ Y1, const bf16_t* __restrict__ Y2,
                 float* __restrict__ O) {
  const int wg = ((int)blockIdx.x & 7) * 48 + ((int)blockIdx.x >> 3);
  const int b = wg / 6, t6 = wg % 6;
  const int mt = t6 / 3, nt = t6 % 3;

  __shared__ __align__(16) char lds[65536];    // 4 bufs x (A 8KB + B 8KB)

  const int t = threadIdx.x;
  const int lane = t & 63, w = t >> 6;
  const int sRow = t >> 2;
  const int sCol8 = (((t & 3) ^ ((t >> 3) & 3))) * 8;   // pre-swizzled source chunk
  const int t16 = t * 16;

  const int i0 = mt * 128 + sRow;
  const int i1 = i0 + 64;
  int j0 = nt * 128 + sRow;      if (j0 > L2C - 1) j0 = L2C - 1;
  int j1 = nt * 128 + sRow + 64; if (j1 > L2C - 1) j1 = L2C - 1;
  const bf16_t* A0 = Y1 + ((size_t)i0 * BC + b) * DC + sCol8;
  const bf16_t* A1 = Y1 + ((size_t)i1 * BC + b) * DC + sCol8;
  const bf16_t* B0 = Y2 + ((size_t)j0 * BC + b) * DC + sCol8;
  const bf16_t* B1 = Y2 + ((size_t)j1 * BC + b) * DC + sCol8;

  const int wr = (w >> 1) * 64, wc = (w & 1) * 64;
  const int rsel = lane & 15, hi = lane >> 4;
  const int kchunk = (hi ^ ((rsel >> 1) & 3)) << 4;
  const int offA = ((wr + rsel) << 6) + kchunk;
  const int offB = 8192 + ((wc + rsel) << 6) + kchunk;

  f32x4 acc[4][4] = {};

  // prologue: stage tiles 0..2
#pragma unroll
  for (int p = 0; p < 3; ++p) {
    char* db = lds + p * 16384;
    gload16(A0 + p * 32, db + t16);
    gload16(A1 + p * 32, db + 4096 + t16);
    gload16(B0 + p * 32, db + 8192 + t16);
    gload16(B1 + p * 32, db + 12288 + t16);
  }
  asm volatile("s_waitcnt vmcnt(8)" ::: "memory");
  __builtin_amdgcn_s_barrier();
  __builtin_amdgcn_sched_barrier(0);

#pragma unroll 1
  for (int tt = 0; tt < 32; ++tt) {
    const char* rb = lds + (tt & 3) * 16384;
    char* sb = lds + ((tt + 3) & 3) * 16384;
    const int ks = (tt + 3) * 32;
    bf16x8 af[4], bfv[4];
#pragma unroll
    for (int m = 0; m < 4; ++m) af[m] = *(const bf16x8*)(rb + offA + m * 1024);
#pragma unroll
    for (int n = 0; n < 4; ++n) bfv[n] = *(const bf16x8*)(rb + offB + n * 1024);
    if (tt < 29) {
      gload16(A0 + ks, sb + t16);
      gload16(A1 + ks, sb + 4096 + t16);
      gload16(B0 + ks, sb + 8192 + t16);
      gload16(B1 + ks, sb + 12288 + t16);
    }
    __builtin_amdgcn_s_setprio(1);
#pragma unroll
    for (int m = 0; m < 4; ++m)
#pragma unroll
      for (int n = 0; n < 4; ++n)
        acc[m][n] = __builtin_amdgcn_mfma_f32_16x16x32_bf16(af[m], bfv[n], acc[m][n], 0, 0, 0);
    __builtin_amdgcn_s_setprio(0);
    if (tt < 29)       asm volatile("s_waitcnt vmcnt(8)" ::: "memory");
    else if (tt == 29) asm volatile("s_waitcnt vmcnt(4)" ::: "memory");
    else if (tt == 30) asm volatile("s_waitcnt vmcnt(0)" ::: "memory");
    __builtin_amdgcn_s_barrier();
    __builtin_amdgcn_sched_barrier(0);
  }

  float* Ob = O + (size_t)b * L1C * L2C;
  const int row0 = mt * 128 + wr + hi * 4;
  const int col0 = nt * 128 + wc + rsel;
#pragma unroll
  for (int n = 0; n < 4; ++n) {
    const int c = col0 + n * 16;
    if (c < L2C) {
#pragma unroll
      for (int m = 0; m < 4; ++m) {
        const int r = row0 + m * 16;
#pragma unroll
        for (int q = 0; q < 4; ++q)
          Ob[(size_t)(r + q) * L2C + c] = acc[m][n][q];
      }
    }
  }
}

// ---------------- softmax stats (with rank-1 terms t1,t2) ----------------
__global__ __launch_bounds__(256)
void row_stats(const float* __restrict__ O, const float* __restrict__ tT2,
               float* __restrict__ rowM, float* __restrict__ rowInv) {
  const int gw = blockIdx.x * 4 + (threadIdx.x >> 6);
  const int lane = threadIdx.x & 63;
  const int b = gw >> 8;
  const float* row = O + (size_t)gw * L2C;
  const float* t2 = tT2 + b * L2C;
  float v[5];
  float m = -1e30f;
#pragma unroll
  for (int t = 0; t < 5; ++t) { v[t] = row[t * 64 + lane] + t2[t * 64 + lane]; m = fmaxf(m, v[t]); }
#pragma unroll
  for (int off = 32; off; off >>= 1) m = fmaxf(m, __shfl_xor(m, off));
  float s = 0.f;
#pragma unroll
  for (int t = 0; t < 5; ++t) s += __expf(v[t] - m);
#pragma unroll
  for (int off = 32; off; off >>= 1) s += __shfl_xor(s, off);
  if (lane == 0) { rowM[gw] = m; rowInv[gw] = 1.f / s; }
}

__global__ __launch_bounds__(256)
void col_stats_c1(const float* __restrict__ O, const float* __restrict__ tT1,
                  const float* __restrict__ tT2,
                  const float* __restrict__ rowM, const float* __restrict__ rowInv,
                  float* __restrict__ colM, float* __restrict__ colInv,
                  float* __restrict__ c1) {
  const int b = blockIdx.x / 5, jb = blockIdx.x % 5;
  const int jl = threadIdx.x & 63, ig = threadIdx.x >> 6;
  const int j = jb * 64 + jl;
  const float* Ob = O + (size_t)b * L1C * L2C + j;
  const float* rM = rowM + b * L1C;
  const float* rI = rowInv + b * L1C;
  const float* t1 = tT1 + b * L1C;
  const float t2j = tT2[b * L2C + j];
  float m = -1e30f, s = 0.f, cp = 0.f;
  for (int i = ig; i < L1C; i += 4) {
    float ov = Ob[(size_t)i * L2C];
    float v = ov + t1[i];
    float mn = fmaxf(m, v);
    s = s * __expf(m - mn) + __expf(v - mn);
    m = mn;
    cp += __expf(ov + t2j - rM[i]) * rI[i];
  }
  __shared__ float sm[4][64], ss[4][64], sc[4][64];
  sm[ig][jl] = m; ss[ig][jl] = s; sc[ig][jl] = cp;
  __syncthreads();
  if (ig == 0) {
    for (int g = 1; g < 4; ++g) {
      float mg = sm[g][jl], sg = ss[g][jl];
      float mn = fmaxf(m, mg);
      s = s * __expf(m - mn) + sg * __expf(mg - mn);
      m = mn;
      cp += sc[g][jl];
    }
    colM[b * L2C + j] = m;
    colInv[b * L2C + j] = 1.f / s;
    c1[b * L2C + j] = cp;
  }
}

__global__ __launch_bounds__(256)
void c2_kernel(const float* __restrict__ O, const float* __restrict__ tT1,
               const float* __restrict__ colM, const float* __restrict__ colInv,
               float* __restrict__ c2) {
  const int gw = blockIdx.x * 4 + (threadIdx.x >> 6);
  const int lane = threadIdx.x & 63;
  const int b = gw >> 8;
  const float* row = O + (size_t)gw * L2C;
  const float* cM = colM + b * L2C;
  const float* cI = colInv + b * L2C;
  const float t1i = tT1[b * L1C + (gw & 255)];
  float s = 0.f;
#pragma unroll
  for (int t = 0; t < 5; ++t) {
    const int j = t * 64 + lane;
    s += __expf(row[j] + t1i - cM[j]) * cI[j];
  }
#pragma unroll
  for (int off = 32; off; off >>= 1) s += __shfl_xor(s, off);
  if (lane == 0) c2[gw] = s;
}

// ---------------- weighted h-sums -> U (256x1024 bf16) ----------------
__global__ __launch_bounds__(256)
void u_kernel(const bf16_t* __restrict__ H, const float* __restrict__ c1,
              const float* __restrict__ c2, bf16_t* __restrict__ Ub) {
  const int b = blockIdx.x >> 2;
  const int d = (blockIdx.x & 3) * 256 + threadIdx.x;
  const bf16_t* H2 = H + (size_t)L1C * BC * DC;
  float s1 = 0.f, s1c = 0.f, s2 = 0.f, s2c = 0.f;
  const float* c2b = c2 + b * L1C;
  for (int i = 0; i < L1C; ++i) {
    float v = (float)H[((size_t)i * BC + b) * DC + d];
    s1 += v; s1c += c2b[i] * v;
  }
  const float* c1b = c1 + b * L2C;
  for (int j = 0; j < L2C; ++j) {
    float v = (float)H2[((size_t)j * BC + b) * DC + d];
    s2 += v; s2c += c1b[j] * v;
  }
  Ub[(size_t)(0 * 64 + b) * 1024 + d] = (bf16_t)(s1  * (1.f / L1C));
  Ub[(size_t)(1 * 64 + b) * 1024 + d] = (bf16_t)(s2c * (1.f / L1C));
  Ub[(size_t)(2 * 64 + b) * 1024 + d] = (bf16_t)(s2  * (1.f / L2C));
  Ub[(size_t)(3 * 64 + b) * 1024 + d] = (bf16_t)(s1c * (1.f / L2C));
}

// ---------------- host ----------------
extern "C" void kernel_launch(void* const* d_in, const int* in_sizes, int n_in,
                              void* d_out, int out_size, void* d_ws, size_t ws_size,
                              hipStream_t stream) {
  const float* r1 = (const float*)d_in[0];
  const float* r2 = (const float*)d_in[1];
  const float* W1 = (const float*)d_in[2];
  const float* b1 = (const float*)d_in[3];
  const float* W2 = (const float*)d_in[4];
  const float* b2 = (const float*)d_in[5];
  float* out = (float*)d_out;
  char* ws = (char*)d_ws;

  const size_t M1 = (size_t)L1C * BC;   // 16384
  const size_t M2 = (size_t)L2C * BC;   // 20480
  const size_t Mt = M1 + M2;            // 36864

  size_t off = 0;
  bf16_t* XB  = (bf16_t*)(ws + off); off += Mt * DC * 2;        // 72MB: A-bf16, then Z + O
  bf16_t* HB  = (bf16_t*)(ws + off); off += Mt * DC * 2;        // 72MB, h; head reused as Ppart
  bf16_t* WB1 = (bf16_t*)(ws + off); off += (size_t)DC * DC * 2;
  bf16_t* WB2 = (bf16_t*)(ws + off); off += (size_t)DC * DC * 2;
  bf16_t* W2T = (bf16_t*)(ws + off); off += (size_t)DC * DC * 2;
  bf16_t* GB  = (bf16_t*)(ws + off); off += (size_t)DC * DC * 2;
  float* w2b   = (float*)(ws + off); off += 4096;
  float* zb    = (float*)(ws + off); off += 4096;
  float* tT1   = (float*)(ws + off); off += BC * L1C * 4;
  float* tT2   = (float*)(ws + off); off += BC * L2C * 4;
  float* rowM  = (float*)(ws + off); off += BC * L1C * 4;
  float* rowIv = (float*)(ws + off); off += BC * L1C * 4;
  float* colM  = (float*)(ws + off); off += BC * L2C * 4;
  float* colIv = (float*)(ws + off); off += BC * L2C * 4;
  float* c1v   = (float*)(ws + off); off += BC * L2C * 4;
  float* c2v   = (float*)(ws + off); off += BC * L1C * 4;
  bf16_t* Ub   = (bf16_t*)(ws + off); off += 256 * DC * 2;

  bf16_t* Z = XB;                                   // 16384x1024 bf16 (32MB)
  float*  O = (float*)((char*)XB + 35651584);       // 21MB logits
  float*  Ppart = (float*)HB;                       // 8MB (8 slices), HB dead then
  bf16_t* H2 = HB + M1 * DC;

  // 1. fused prep (converts + W2T + w2b + zb)
  prep_kernel<<<10817, 256, 0, stream>>>(r1, r2, XB, W1, WB1, W2, WB2, W2T,
                                         b2, w2b, zb);

  // 2. fused: G = W2T.W2T^T (blocks 0..63) + h = relu(x W1^T + b1) (rest)
  g1g_kernel<<<2368, 256, 0, stream>>>(XB, WB1, b1, HB, W2T, GB);

  // 3. t = h . (W2^T b2)
  t_kernel<<<9216, 256, 0, stream>>>(HB, w2b, tT1, tT2);

  // 4. z1 = h1 G
  mlp_gemm8<<<256, 512, 0, stream>>>(HB, GB, zb, Z, 64, 0);

  // 5. oz[b,i,j] = z1 . h2
  logits_gemm<<<384, 256, 0, stream>>>(Z, H2, O);

  // 6. softmax stats with rank-1 corrections
  row_stats<<<4096, 256, 0, stream>>>(O, tT2, rowM, rowIv);
  col_stats_c1<<<320, 256, 0, stream>>>(O, tT1, tT2, rowM, rowIv, colM, colIv, c1v);
  c2_kernel<<<4096, 256, 0, stream>>>(O, tT1, colM, colIv, c2v);

  // 7. weighted h pools -> U;  out = U W2^T + b2, split-K + reduce
  u_kernel<<<256, 256, 0, stream>>>(HB, c1v, c2v, Ub);
  pool_gemmK<<<128, 256, 0, stream>>>(Ub, WB2, Ppart);
  pool_reduce<<<1024, 256, 0, stream>>>(Ppart, b2, out);
}